// Round 3
// baseline (197.232 us; speedup 1.0000x reference)
//
#include <hip/hip_runtime.h>

// PatchesCreate: images [B=64, H=384, W=384, C=3] f32 (NHWC) ->
// patches [B, 576, 768] f32, P=16, G=24.
//
// v4 == v3 with ALL nontemporal hints removed (single-variable A/B).
// Rationale: v0 (direct gather, no LDS/barriers), v2 (one-shot LDS), v3
// (pipelined persistent LDS) all plateau at 185-193 us (~4.9 TB/s effective),
// while plain-access references on the same box run 6.3-6.7 TB/s. The only
// factor common to all three variants and absent from the references is the
// `nt` MUBUF flag on every global access. Hypothesis: nt demotes requests in
// the L2/MALL path and caps streaming BW ~22% below plain accesses.
//
// Structure (unchanged from v3): persistent, 1024 WGs (4/CU, LDS 36,992 B),
// 3 half-slab tiles per WG, register prefetch of tile i+1 before tile i's
// barriers, raw s_barrier + manual lgkmcnt(0) so prefetch loads and stores
// stay in flight across barriers. Both global streams long-sequential.

typedef float f4 __attribute__((ext_vector_type(4)));

constexpr int C     = 3;
constexpr int P     = 16;
constexpr int G     = 24;                 // 384/16
constexpr int ROW4  = 384 * C / 4;        // 288 float4 per image row
constexpr int IMG4  = 384 * ROW4;         // 110592 float4 per image (in == out)
constexpr int HR    = 8;                  // image rows staged per tile
constexpr int TILE4 = HR * ROW4;          // 2304 float4 = 36 KiB
constexpr int LSTR  = ROW4 + 1;           // 289: +16 B pad per LDS row
constexpr int BLOCK = 256;
constexpr int PT    = TILE4 / BLOCK;      // 9 float4 per thread (exact)
constexpr int NSLAB = 64 * G * 2;         // 3072 half-slabs
constexpr int GRID  = 1024;               // 4 WGs/CU resident, persistent
constexpr int NITER = NSLAB / GRID;       // 3 tiles per WG

constexpr int GY4   = G * P * P * C / 4;  // 4608 f4 per gy-group of patches
constexpr int HALF4 = HR * P * C / 4;     // 96 f4: half-patch offset

__device__ __forceinline__ int in_base_of(int s) {
    int half = s & 1, bg = s >> 1;
    int gy = bg % G, b = bg / G;
    return b * IMG4 + (gy * P + half * HR) * ROW4;
}
__device__ __forceinline__ int out_base_of(int s) {
    int half = s & 1, bg = s >> 1;
    int gy = bg % G, b = bg / G;
    return b * IMG4 + gy * GY4 + half * HALF4;
}

__global__ __launch_bounds__(BLOCK, 4)
void patches_kernel(const f4* __restrict__ in, f4* __restrict__ out) {
    __shared__ f4 lds[HR * LSTR];         // 36,992 B -> 4 WGs/CU
    const int t  = threadIdx.x;
    const int s0 = blockIdx.x;

    f4 v[PT], u[PT];
    {
        const f4* p = in + in_base_of(s0) + t;
#pragma unroll
        for (int j = 0; j < PT; ++j)
            v[j] = p[j * BLOCK];
    }

#pragma unroll
    for (int i = 0; i < NITER; ++i) {
        // ---- prefetch tile i+1 into registers (stays in flight all iter)
        if (i + 1 < NITER) {
            const f4* p = in + in_base_of(s0 + (i + 1) * GRID) + t;
#pragma unroll
            for (int j = 0; j < PT; ++j)
                u[j] = p[j * BLOCK];
            __builtin_amdgcn_sched_barrier(0);   // pin load issue above barriers
        }

        if (i > 0)
            __builtin_amdgcn_s_barrier();  // WAR: all waves done reading prev tile

        // ---- ds_write v (compiler waits precisely for v's loads, not u's)
#pragma unroll
        for (int j = 0; j < PT; ++j) {
            int idx = t + j * BLOCK;
            int row = idx / ROW4;          // 0..7
            int col = idx - row * ROW4;    // 0..287
            lds[row * LSTR + col] = v[j];
        }
        asm volatile("s_waitcnt lgkmcnt(0)" ::: "memory");
        __builtin_amdgcn_s_barrier();      // tile i visible to all waves

        // ---- gather in output order, coalesced stores
        const int ob = out_base_of(s0 + i * GRID);
#pragma unroll
        for (int j = 0; j < PT; ++j) {
            int o  = t + j * BLOCK;        // 0..2303
            int gx = o / 96;               // 0..23
            int w  = o - gx * 96;          // py*12 + k
            int py = w / 12;
            int k  = w - py * 12;
            out[ob + gx * 192 + w] = lds[py * LSTR + gx * 12 + k];
        }

        if (i + 1 < NITER) {
#pragma unroll
            for (int j = 0; j < PT; ++j) v[j] = u[j];
        }
    }
}

extern "C" void kernel_launch(void* const* d_in, const int* in_sizes, int n_in,
                              void* d_out, int out_size, void* d_ws, size_t ws_size,
                              hipStream_t stream) {
    const f4* in  = (const f4*)d_in[0];
    f4*       out = (f4*)d_out;
    patches_kernel<<<GRID, BLOCK, 0, stream>>>(in, out);
}

// Round 4
// 195.319 us; speedup vs baseline: 1.0098x; 1.0098x over previous
//
#include <hip/hip_runtime.h>

// PatchesCreate: images [B=64, H=384, W=384, C=3] f32 (NHWC) ->
// patches [B, 576, 768] f32, P=16, G=24.
//
// v5 = v3/v4 structure with PLAIN loads + NONTEMPORAL stores.
//
// Round-3 evidence: input is 113 MB and fits the 256 MB Infinity Cache;
// v4 (plain loads+stores) showed FETCH_SIZE = 55 MB, i.e. half the input
// stayed cache-resident across dispatches and half was evicted by our own
// 113 MB of allocating output stores. NT-everything (v3, ~56 us dispatch)
// beat plain-everything (v4, 68.5 us), but NT loads forfeit input residency.
// Hypothesis: plain loads (input stays L3-resident -> reads become cache
// hits) + NT stores (output streams to HBM without evicting input) is
// strictly better than both. Single-variable vs BOTH v3 and v4.
//
// Structure (unchanged): persistent, 1024 WGs, LDS 36,992 B, 3 half-slab
// tiles per WG, register prefetch of tile i+1 before tile i's barriers,
// raw s_barrier + manual lgkmcnt(0); both global streams long-sequential.

typedef float f4 __attribute__((ext_vector_type(4)));

constexpr int C     = 3;
constexpr int P     = 16;
constexpr int G     = 24;                 // 384/16
constexpr int ROW4  = 384 * C / 4;        // 288 float4 per image row
constexpr int IMG4  = 384 * ROW4;         // 110592 float4 per image (in == out)
constexpr int HR    = 8;                  // image rows staged per tile
constexpr int TILE4 = HR * ROW4;          // 2304 float4 = 36 KiB
constexpr int LSTR  = ROW4 + 1;           // 289: +16 B pad per LDS row
constexpr int BLOCK = 256;
constexpr int PT    = TILE4 / BLOCK;      // 9 float4 per thread (exact)
constexpr int NSLAB = 64 * G * 2;         // 3072 half-slabs
constexpr int GRID  = 1024;               // persistent grid
constexpr int NITER = NSLAB / GRID;       // 3 tiles per WG

constexpr int GY4   = G * P * P * C / 4;  // 4608 f4 per gy-group of patches
constexpr int HALF4 = HR * P * C / 4;     // 96 f4: half-patch offset

__device__ __forceinline__ int in_base_of(int s) {
    int half = s & 1, bg = s >> 1;
    int gy = bg % G, b = bg / G;
    return b * IMG4 + (gy * P + half * HR) * ROW4;
}
__device__ __forceinline__ int out_base_of(int s) {
    int half = s & 1, bg = s >> 1;
    int gy = bg % G, b = bg / G;
    return b * IMG4 + gy * GY4 + half * HALF4;
}

__global__ __launch_bounds__(BLOCK, 4)
void patches_kernel(const f4* __restrict__ in, f4* __restrict__ out) {
    __shared__ f4 lds[HR * LSTR];         // 36,992 B
    const int t  = threadIdx.x;
    const int s0 = blockIdx.x;

    f4 v[PT], u[PT];
    {
        const f4* p = in + in_base_of(s0) + t;
#pragma unroll
        for (int j = 0; j < PT; ++j)
            v[j] = p[j * BLOCK];          // plain load: keep input L3-resident
    }

#pragma unroll
    for (int i = 0; i < NITER; ++i) {
        // ---- prefetch tile i+1 into registers (stays in flight all iter)
        if (i + 1 < NITER) {
            const f4* p = in + in_base_of(s0 + (i + 1) * GRID) + t;
#pragma unroll
            for (int j = 0; j < PT; ++j)
                u[j] = p[j * BLOCK];      // plain load
            __builtin_amdgcn_sched_barrier(0);   // pin load issue above barriers
        }

        if (i > 0)
            __builtin_amdgcn_s_barrier();  // WAR: all waves done reading prev tile

        // ---- ds_write v (compiler waits precisely for v's loads, not u's)
#pragma unroll
        for (int j = 0; j < PT; ++j) {
            int idx = t + j * BLOCK;
            int row = idx / ROW4;          // 0..7
            int col = idx - row * ROW4;    // 0..287
            lds[row * LSTR + col] = v[j];
        }
        asm volatile("s_waitcnt lgkmcnt(0)" ::: "memory");
        __builtin_amdgcn_s_barrier();      // tile i visible to all waves

        // ---- gather in output order; NT stores: stream out without
        //      evicting the cache-resident input
        const int ob = out_base_of(s0 + i * GRID);
#pragma unroll
        for (int j = 0; j < PT; ++j) {
            int o  = t + j * BLOCK;        // 0..2303
            int gx = o / 96;               // 0..23
            int w  = o - gx * 96;          // py*12 + k
            int py = w / 12;
            int k  = w - py * 12;
            f4 x = lds[py * LSTR + gx * 12 + k];
            __builtin_nontemporal_store(x, out + ob + gx * 192 + w);
        }

        if (i + 1 < NITER) {
#pragma unroll
            for (int j = 0; j < PT; ++j) v[j] = u[j];
        }
    }
}

extern "C" void kernel_launch(void* const* d_in, const int* in_sizes, int n_in,
                              void* d_out, int out_size, void* d_ws, size_t ws_size,
                              hipStream_t stream) {
    const f4* in  = (const f4*)d_in[0];
    f4*       out = (f4*)d_out;
    patches_kernel<<<GRID, BLOCK, 0, stream>>>(in, out);
}

// Round 5
// 185.751 us; speedup vs baseline: 1.0618x; 1.0515x over previous
//
#include <hip/hip_runtime.h>

// PatchesCreate: images [B=64, H=384, W=384, C=3] f32 (NHWC) ->
// patches [B, 576, 768] f32, P=16, G=24.
//
// v6: BARRIER-FREE wave-private LDS pipeline, NT loads + NT stores.
//
// Evidence: v3 (NT/NT, WG barriers) = 56.8 us dispatch; plain loads are
// 10 us WORSE (v4/v5) -> keep NT both sides. Kernel shows VALUBusy 2.6%,
// Occ 27%, HBM 2.5 TB/s: the machine is idle-waiting, not bandwidth-capped.
// Remaining common factor: per-tile WG-wide barrier pair couples the 4 waves
// of each WG in lockstep -> memory pipes go unfed at every phase boundary.
//
// Fix: the permutation factorizes to ROW-PAIRS. Rows (2p, 2p+1) of a slab
// (b,gy) are 9 KiB contiguous input, and map to output offset p*24 f4 inside
// each of the 24 patches of that slab row: 24 aligned 384 B runs. One WAVE
// stages one row-pair in its own private 2x289-f4 LDS region:
//   load(9xf4) -> ds_write -> ds_read(gather) -> store, no __syncthreads
// anywhere. Same-wave DS ordering + explicit lgkmcnt(0) (insurance) give
// cross-lane visibility. Waves never couple; 16 independent waves/CU keep
// both HBM directions continuously outstanding.
//
// Persistent: 1024 WGs x 4 waves = 4096 waves x 3 tiles = 12288 row-pairs.
// Depth-1 register prefetch of tile i+1 issued before tile i's LDS phase.

typedef float f4 __attribute__((ext_vector_type(4)));

constexpr int ROW4  = 288;                // f4 per image row
constexpr int IMG4  = 384 * ROW4;         // 110592 f4 per image (in == out)
constexpr int GY4   = 24 * 192;           // 4608 f4 per gy-slab of patches
constexpr int LROW  = ROW4 + 1;           // 289: +16 B pad per LDS row
constexpr int LWAVE = 2 * LROW;           // 578 f4 per wave region
constexpr int BLOCK = 256;                // 4 waves
constexpr int GRID  = 1024;               // persistent; 4 WGs/CU
constexpr int NW    = GRID * 4;           // 4096 waves
constexpr int NTILE = 64 * 24 * 8;        // 12288 row-pair tiles
constexpr int NITER = NTILE / NW;         // 3 tiles per wave
constexpr int PT    = 9;                  // f4 per lane per tile (576/64)

__device__ __forceinline__ int in_base_of(int tau) {
    int p = tau & 7, t2 = tau >> 3;
    int gy = t2 % 24, b = t2 / 24;
    return b * IMG4 + (gy * 16 + 2 * p) * ROW4;
}
__device__ __forceinline__ int out_base_of(int tau) {
    int p = tau & 7, t2 = tau >> 3;
    int gy = t2 % 24, b = t2 / 24;
    return b * IMG4 + gy * GY4 + p * 24;
}

__global__ __launch_bounds__(BLOCK, 4)
void patches_kernel(const f4* __restrict__ in, f4* __restrict__ out) {
    __shared__ f4 lds[4 * LWAVE];         // 36,992 B -> 4 WGs/CU
    const int wv = threadIdx.x >> 6;
    const int l  = threadIdx.x & 63;
    f4* __restrict__ L = &lds[wv * LWAVE];
    const int W = blockIdx.x * 4 + wv;    // global wave id, consecutive tiles

    f4 v[PT], u[PT];
    {
        const f4* p = in + in_base_of(W) + l;
#pragma unroll
        for (int j = 0; j < PT; ++j)
            v[j] = __builtin_nontemporal_load(p + j * 64);
    }

#pragma unroll
    for (int i = 0; i < NITER; ++i) {
        // ---- prefetch tile i+1 (stays in flight through this tile's work)
        if (i + 1 < NITER) {
            const f4* p = in + in_base_of(W + (i + 1) * NW) + l;
#pragma unroll
            for (int j = 0; j < PT; ++j)
                u[j] = __builtin_nontemporal_load(p + j * 64);
            __builtin_amdgcn_sched_barrier(0);   // pin issue point
        }

        // ---- ds_write own tile (compiler waits precisely on v's loads)
#pragma unroll
        for (int j = 0; j < PT; ++j) {
            int idx = l + j * 64;                // 0..575
            int r   = idx / ROW4;                // 0 or 1
            int c   = idx - r * ROW4;            // 0..287
            L[r * LROW + c] = v[j];
        }
        asm volatile("s_waitcnt lgkmcnt(0)" ::: "memory");
        __builtin_amdgcn_sched_barrier(0);       // no read hoisted above wait

        // ---- gather in output order, NT stores (24 x 384 B aligned runs)
        const int ob = out_base_of(W + i * NW);
#pragma unroll
        for (int j = 0; j < PT; ++j) {
            int o   = l + j * 64;                // 0..575
            int gx  = o / 24;                    // 0..23
            int w2  = o - gx * 24;               // py2*12 + k
            int py2 = w2 / 12;
            int k   = w2 - py2 * 12;
            f4 x = L[py2 * LROW + gx * 12 + k];
            __builtin_nontemporal_store(x, out + ob + gx * 192 + w2);
        }

        if (i + 1 < NITER) {
#pragma unroll
            for (int j = 0; j < PT; ++j) v[j] = u[j];
        }
    }
}

extern "C" void kernel_launch(void* const* d_in, const int* in_sizes, int n_in,
                              void* d_out, int out_size, void* d_ws, size_t ws_size,
                              hipStream_t stream) {
    const f4* in  = (const f4*)d_in[0];
    f4*       out = (f4*)d_out;
    patches_kernel<<<GRID, BLOCK, 0, stream>>>(in, out);
}